// Round 1
// baseline (157.098 us; speedup 1.0000x reference)
//
#include <hip/hip_runtime.h>

// UV_Aggregator: B=4096, L=50, D=64. One wave per b; MFMA f16 16x16x32.
// Rows = neighbors (padded 50->64 = 4 M-tiles), cols = feature dims (4 N-tiles).

#define LNB 50   // neighbors per node

typedef _Float16 f16x8 __attribute__((ext_vector_type(8)));
typedef float    f32x4 __attribute__((ext_vector_type(4)));

struct __align__(16) SMem {
  _Float16 h[64 * 64];   // H then A1-out (a), XOR-swizzled rows
  _Float16 o[64 * 64];   // O, XOR-swizzled rows
  int   iu[64];
  int   ir[64];
  float sc[64];
  float wt[64];
};

// byte offset into a [64][64] f16 tile (128 B rows), T2-style XOR swizzle
__device__ __forceinline__ int swz(int r, int bytecol) {
  return (r * 128 + bytecol) ^ ((r & 7) << 4);
}

__device__ __forceinline__ f16x8 cvt8(const float* __restrict__ p) {
  const float4 lo = *(const float4*)p;
  const float4 hi = *(const float4*)(p + 4);
  f16x8 a;
  a[0] = (_Float16)lo.x; a[1] = (_Float16)lo.y;
  a[2] = (_Float16)lo.z; a[3] = (_Float16)lo.w;
  a[4] = (_Float16)hi.x; a[5] = (_Float16)hi.y;
  a[6] = (_Float16)hi.z; a[7] = (_Float16)hi.w;
  return a;
}

// convert fp32 weights to f16 into workspace (re-run every call; ws is re-poisoned)
__global__ void prep_weights(const float* __restrict__ w1, const float* __restrict__ w2,
                             const float* __restrict__ a1, const float* __restrict__ a2,
                             _Float16* __restrict__ wf) {
  int i = blockIdx.x * 256 + threadIdx.x;
  if (i < 8192) wf[i]         = (_Float16)w1[i];   // w_r1_w (64x128)
  if (i < 4096) wf[8192 + i]  = (_Float16)w2[i];   // w_r2_w (64x64)
  if (i < 8192) wf[12288 + i] = (_Float16)a1[i];   // att1_w (64x128)
  if (i < 4096) wf[20480 + i] = (_Float16)a2[i];   // att2_w (64x64)
}

__global__ __launch_bounds__(64, 2) void uvagg_kernel(
    const int* __restrict__ nodes,
    const int* __restrict__ hist_uv,
    const int* __restrict__ hist_r,
    const float* __restrict__ v2e,
    const float* __restrict__ u2e,
    const float* __restrict__ r2e,
    const float* __restrict__ b1,
    const float* __restrict__ b2,
    const float* __restrict__ ab1,
    const float* __restrict__ ab2,
    const float* __restrict__ a3w,
    const _Float16* __restrict__ wf,
    float* __restrict__ out) {
  __shared__ SMem W;
  const int lane = threadIdx.x;
  const int b = blockIdx.x;
  const int lr = lane & 15;   // A row-in-tile / B,C col-in-tile
  const int kq = lane >> 4;   // 0..3 (k-phase: 8 contiguous k per lane)

  if (lane < LNB) {
    W.iu[lane] = hist_uv[b * LNB + lane];
    W.ir[lane] = hist_r[b * LNB + lane];
  } else {
    W.iu[lane] = 0;
    W.ir[lane] = 0;
  }
  const int node = nodes[b];
  __syncthreads();

  const _Float16* w1f = wf;
  const _Float16* w2f = wf + 8192;
  const _Float16* a1f = wf + 12288;
  const _Float16* a2f = wf + 20480;

  // ---------------- Layer 1: H = relu(X @ W1^T + b1), X = [e_uv ; e_r] ----
  {
    f16x8 Bf[4][4];
#pragma unroll
    for (int kt = 0; kt < 4; ++kt)
#pragma unroll
      for (int nt = 0; nt < 4; ++nt)
        Bf[kt][nt] = *(const f16x8*)(w1f + (nt * 16 + lr) * 128 + kt * 32 + kq * 8);

#pragma unroll
    for (int m = 0; m < 4; ++m) {
      const int r = m * 16 + lr;
      f16x8 A[4];
      if (r < LNB) {
        const float* pu = v2e + (size_t)W.iu[r] * 64;
        const float* pr = r2e + (size_t)W.ir[r] * 64;
        A[0] = cvt8(pu + kq * 8);
        A[1] = cvt8(pu + 32 + kq * 8);
        A[2] = cvt8(pr + kq * 8);
        A[3] = cvt8(pr + 32 + kq * 8);
      } else {
#pragma unroll
        for (int kt = 0; kt < 4; ++kt)
#pragma unroll
          for (int i = 0; i < 8; ++i) A[kt][i] = (_Float16)0.f;
      }
#pragma unroll
      for (int nt = 0; nt < 4; ++nt) {
        f32x4 acc = {0.f, 0.f, 0.f, 0.f};
#pragma unroll
        for (int kt = 0; kt < 4; ++kt)
          acc = __builtin_amdgcn_mfma_f32_16x16x32_f16(A[kt], Bf[kt][nt], acc, 0, 0, 0);
        const int c = nt * 16 + lr;
        const float bias = b1[c];
#pragma unroll
        for (int j = 0; j < 4; ++j) {
          const int row = m * 16 + kq * 4 + j;
          const float v = fmaxf(acc[j] + bias, 0.f);
          *(_Float16*)((char*)W.h + swz(row, 2 * c)) = (_Float16)v;
        }
      }
    }
  }
  __syncthreads();

  // ---------------- Layer 2: O = relu(H @ W2^T + b2) ----------------------
  {
    f16x8 Bf[2][4];
#pragma unroll
    for (int kt = 0; kt < 2; ++kt)
#pragma unroll
      for (int nt = 0; nt < 4; ++nt)
        Bf[kt][nt] = *(const f16x8*)(w2f + (nt * 16 + lr) * 64 + kt * 32 + kq * 8);

#pragma unroll
    for (int m = 0; m < 4; ++m) {
      const int r = m * 16 + lr;
      f16x8 A0 = *(const f16x8*)((char*)W.h + swz(r, 2 * (kq * 8)));
      f16x8 A1v = *(const f16x8*)((char*)W.h + swz(r, 2 * (32 + kq * 8)));
#pragma unroll
      for (int nt = 0; nt < 4; ++nt) {
        f32x4 acc = {0.f, 0.f, 0.f, 0.f};
        acc = __builtin_amdgcn_mfma_f32_16x16x32_f16(A0, Bf[0][nt], acc, 0, 0, 0);
        acc = __builtin_amdgcn_mfma_f32_16x16x32_f16(A1v, Bf[1][nt], acc, 0, 0, 0);
        const int c = nt * 16 + lr;
        const float bias = b2[c];
#pragma unroll
        for (int j = 0; j < 4; ++j) {
          const int row = m * 16 + kq * 4 + j;
          const float v = fmaxf(acc[j] + bias, 0.f);
          *(_Float16*)((char*)W.o + swz(row, 2 * c)) = (_Float16)v;
        }
      }
    }
  }
  __syncthreads();

  // ---------------- Att layer 1: P = relu([O ; uv_rep] @ A1^T + ab1) ------
  {
    f16x8 Bf[4][4];
#pragma unroll
    for (int kt = 0; kt < 4; ++kt)
#pragma unroll
      for (int nt = 0; nt < 4; ++nt)
        Bf[kt][nt] = *(const f16x8*)(a1f + (nt * 16 + lr) * 128 + kt * 32 + kq * 8);

    // uv_rep halves are row-independent
    const f16x8 U2 = cvt8(u2e + (size_t)node * 64 + kq * 8);
    const f16x8 U3 = cvt8(u2e + (size_t)node * 64 + 32 + kq * 8);

#pragma unroll
    for (int m = 0; m < 4; ++m) {
      const int r = m * 16 + lr;
      f16x8 A0 = *(const f16x8*)((char*)W.o + swz(r, 2 * (kq * 8)));
      f16x8 A1v = *(const f16x8*)((char*)W.o + swz(r, 2 * (32 + kq * 8)));
#pragma unroll
      for (int nt = 0; nt < 4; ++nt) {
        f32x4 acc = {0.f, 0.f, 0.f, 0.f};
        acc = __builtin_amdgcn_mfma_f32_16x16x32_f16(A0, Bf[0][nt], acc, 0, 0, 0);
        acc = __builtin_amdgcn_mfma_f32_16x16x32_f16(A1v, Bf[1][nt], acc, 0, 0, 0);
        acc = __builtin_amdgcn_mfma_f32_16x16x32_f16(U2, Bf[2][nt], acc, 0, 0, 0);
        acc = __builtin_amdgcn_mfma_f32_16x16x32_f16(U3, Bf[3][nt], acc, 0, 0, 0);
        const int c = nt * 16 + lr;
        const float bias = ab1[c];
#pragma unroll
        for (int j = 0; j < 4; ++j) {
          const int row = m * 16 + kq * 4 + j;
          const float v = fmaxf(acc[j] + bias, 0.f);
          *(_Float16*)((char*)W.h + swz(row, 2 * c)) = (_Float16)v;
        }
      }
    }
  }
  __syncthreads();

  // ---------------- Att layer 2 + scores: s = relu(P @ A2^T + ab2) . a3 ---
  {
    f16x8 Bf[2][4];
#pragma unroll
    for (int kt = 0; kt < 2; ++kt)
#pragma unroll
      for (int nt = 0; nt < 4; ++nt)
        Bf[kt][nt] = *(const f16x8*)(a2f + (nt * 16 + lr) * 64 + kt * 32 + kq * 8);

#pragma unroll
    for (int m = 0; m < 4; ++m) {
      const int r = m * 16 + lr;
      f16x8 A0 = *(const f16x8*)((char*)W.h + swz(r, 2 * (kq * 8)));
      f16x8 A1v = *(const f16x8*)((char*)W.h + swz(r, 2 * (32 + kq * 8)));
      float part[4] = {0.f, 0.f, 0.f, 0.f};
#pragma unroll
      for (int nt = 0; nt < 4; ++nt) {
        f32x4 acc = {0.f, 0.f, 0.f, 0.f};
        acc = __builtin_amdgcn_mfma_f32_16x16x32_f16(A0, Bf[0][nt], acc, 0, 0, 0);
        acc = __builtin_amdgcn_mfma_f32_16x16x32_f16(A1v, Bf[1][nt], acc, 0, 0, 0);
        const int c = nt * 16 + lr;
        const float bias = ab2[c];
        const float a3c = a3w[c];
#pragma unroll
        for (int j = 0; j < 4; ++j) {
          const float v = fmaxf(acc[j] + bias, 0.f);
          part[j] += v * a3c;
        }
      }
      // reduce over the 16 lanes sharing kq (cols) -> per-row score
#pragma unroll
      for (int mask = 1; mask < 16; mask <<= 1)
#pragma unroll
        for (int j = 0; j < 4; ++j) part[j] += __shfl_xor(part[j], mask);
      if (lr == 0) {
#pragma unroll
        for (int j = 0; j < 4; ++j) W.sc[m * 16 + kq * 4 + j] = part[j];
      }
    }
  }
  __syncthreads();

  // ---------------- softmax over neighbors (att3_b is softmax-invariant) --
  {
    float sv = (lane < LNB) ? W.sc[lane] : -1e30f;
    float mx = sv;
#pragma unroll
    for (int mask = 1; mask < 64; mask <<= 1) mx = fmaxf(mx, __shfl_xor(mx, mask));
    const float e = __expf(sv - mx);
    float s = e;
#pragma unroll
    for (int mask = 1; mask < 64; mask <<= 1) s += __shfl_xor(s, mask);
    W.wt[lane] = e / s;
  }
  __syncthreads();

  // ---------------- weighted sum: out[b][d] = sum_l wt[l] * O[l][d] -------
  {
    float acc = 0.f;
    for (int l = 0; l < LNB; ++l) {
      const float wl = W.wt[l];
      const float ov = (float)(*(const _Float16*)((const char*)W.o + swz(l, 2 * lane)));
      acc += wl * ov;
    }
    out[(size_t)b * 64 + lane] = acc;
  }
}

extern "C" void kernel_launch(void* const* d_in, const int* in_sizes, int n_in,
                              void* d_out, int out_size, void* d_ws, size_t ws_size,
                              hipStream_t stream) {
  (void)in_sizes; (void)n_in; (void)out_size; (void)ws_size;
  const int* nodes = (const int*)d_in[0];
  const int* huv   = (const int*)d_in[1];
  const int* hr    = (const int*)d_in[2];
  // d_in[3] history_uvt: unused by reference
  const float* v2e = (const float*)d_in[4];
  const float* u2e = (const float*)d_in[5];
  const float* r2e = (const float*)d_in[6];
  const float* w1  = (const float*)d_in[7];
  const float* b1  = (const float*)d_in[8];
  const float* w2  = (const float*)d_in[9];
  const float* b2  = (const float*)d_in[10];
  const float* a1  = (const float*)d_in[11];
  const float* ab1 = (const float*)d_in[12];
  const float* a2  = (const float*)d_in[13];
  const float* ab2 = (const float*)d_in[14];
  const float* a3  = (const float*)d_in[15];
  // d_in[16] att3_b: constant shift inside softmax -> no effect on output

  _Float16* wf = (_Float16*)d_ws;  // 24576 f16 = 48 KB
  prep_weights<<<32, 256, 0, stream>>>(w1, w2, a1, a2, wf);
  uvagg_kernel<<<4096, 64, 0, stream>>>(nodes, huv, hr, v2e, u2e, r2e,
                                        b1, b2, ab1, ab2, a3, wf,
                                        (float*)d_out);
}